// Round 6
// baseline (4792.935 us; speedup 1.0000x reference)
//
#include <hip/hip_runtime.h>
#include <math.h>

// Problem dims
#define SSRC 50
#define NBATCH 64
#define EDIM 300
#define HDIM 512
#define G4H 2048
#define VTGT 10000
#define TSTEPS 49

// Transposed-interleaved state layout: value (k, n) lives at float index
//   (k>>2)*256 + n*4 + (k&3)   i.e. float4 index [k/4][n], lane-coalesced.
#define HS4 8192          // float4 count of one 64x512 state (32768 floats)

// ---------------------------------------------------------------------------
// Agent-coherent (sc1, L2-bypassing, L3-coherent) accessors for MUTABLE shared
// state. Read-only data uses normal cached loads; the barrier below performs
// no cache maintenance, so cached read-only data stays L2-resident.
// ---------------------------------------------------------------------------
__device__ __forceinline__ float ld1_agent(const float* p) {
    return __hip_atomic_load(p, __ATOMIC_RELAXED, __HIP_MEMORY_SCOPE_AGENT);
}
__device__ __forceinline__ void st1_agent(float* p, float v) {
    __hip_atomic_store(p, v, __ATOMIC_RELAXED, __HIP_MEMORY_SCOPE_AGENT);
}
__device__ __forceinline__ float2 ld2_agent(const float* p) {
    unsigned long long u = __hip_atomic_load((const unsigned long long*)p,
                                             __ATOMIC_RELAXED, __HIP_MEMORY_SCOPE_AGENT);
    union { unsigned long long u; float2 f; } c; c.u = u; return c.f;
}

// ---------------------------------------------------------------------------
// Fence-free device barrier (R4/R5-verified). sc1 traffic drains via vmcnt(0);
// relaxed counter add + relaxed poll; timeout so a residency violation fails
// verification instead of hanging.
// ---------------------------------------------------------------------------
__device__ __forceinline__ void gbar(int* cnt, int nblk, int& gen)
{
    asm volatile("s_waitcnt vmcnt(0)" ::: "memory");
    __syncthreads();
    if (threadIdx.x == 0) {
        __hip_atomic_fetch_add(cnt, 1, __ATOMIC_RELAXED, __HIP_MEMORY_SCOPE_AGENT);
        gen += nblk;
        const long long t0 = (long long)__builtin_amdgcn_s_memrealtime();
        while (__hip_atomic_load(cnt, __ATOMIC_RELAXED, __HIP_MEMORY_SCOPE_AGENT) < gen) {
            __builtin_amdgcn_s_sleep(2);
            if ((long long)__builtin_amdgcn_s_memrealtime() - t0 > 200000000LL) break;
        }
    }
    __syncthreads();
}

// ---------------------------------------------------------------------------
// Generic tiled fp32 GEMM (R4-verified, LDS XOR-swizzle).
// ---------------------------------------------------------------------------
__device__ __forceinline__ int gswz(int kk, int c) {
    return kk * 128 + ((c ^ (((c >> 6) & 1) << 2)) ^ (kk << 2));
}

__global__ __launch_bounds__(256)
void gemm_bias_kernel(const float* __restrict__ A, const int* __restrict__ aidx, int lda,
                      const float* __restrict__ B, int ldb,
                      const float* __restrict__ bias,
                      float* __restrict__ C, int ldc,
                      int M, int N, int K, int a_trans)
{
    __shared__ float As[8 * 128];
    __shared__ float Bs[8 * 128];
    const int tid = threadIdx.x;
    const int bm = blockIdx.y * 128;
    const int bn = blockIdx.x * 128;
    const int tx = tid & 15;
    const int ty = tid >> 4;

    float acc[8][8];
#pragma unroll
    for (int i = 0; i < 8; ++i)
#pragma unroll
        for (int j = 0; j < 8; ++j) acc[i][j] = 0.f;

    for (int k0 = 0; k0 < K; k0 += 8) {
#pragma unroll
        for (int i = 0; i < 4; ++i) {
            int idx = tid + i * 256;
            {
                int r, kk;
                if (a_trans) { r = idx & 127; kk = idx >> 7; }
                else         { r = idx >> 3; kk = idx & 7; }
                int gm = bm + r, gk = k0 + kk;
                float va = 0.f;
                if (gm < M && gk < K) {
                    if (a_trans) va = A[(long)gk * lda + gm];
                    else {
                        long arow = aidx ? (long)aidx[gm] : (long)gm;
                        va = A[arow * (long)lda + gk];
                    }
                }
                As[gswz(kk, r)] = va;
            }
            {
                int r = idx >> 3, kk = idx & 7;
                int gn = bn + r, gk = k0 + kk;
                float vb = 0.f;
                if (gn < N && gk < K) vb = B[(long)gn * ldb + gk];
                Bs[gswz(kk, r)] = vb;
            }
        }
        __syncthreads();
#pragma unroll
        for (int kk = 0; kk < 8; ++kk) {
            const float4 a0 = *reinterpret_cast<const float4*>(&As[gswz(kk, ty * 8)]);
            const float4 a1 = *reinterpret_cast<const float4*>(&As[gswz(kk, ty * 8 + 4)]);
            const float4 b0 = *reinterpret_cast<const float4*>(&Bs[gswz(kk, tx * 8)]);
            const float4 b1 = *reinterpret_cast<const float4*>(&Bs[gswz(kk, tx * 8 + 4)]);
            const float a[8] = {a0.x, a0.y, a0.z, a0.w, a1.x, a1.y, a1.z, a1.w};
            const float b[8] = {b0.x, b0.y, b0.z, b0.w, b1.x, b1.y, b1.z, b1.w};
#pragma unroll
            for (int i = 0; i < 8; ++i)
#pragma unroll
                for (int j = 0; j < 8; ++j)
                    acc[i][j] = fmaf(a[i], b[j], acc[i][j]);
        }
        __syncthreads();
    }

#pragma unroll
    for (int i = 0; i < 8; ++i) {
        int m = bm + ty * 8 + i;
        if (m >= M) continue;
#pragma unroll
        for (int j = 0; j < 8; ++j) {
            int n = bn + tx * 8 + j;
            if (n >= N) continue;
            float v = acc[i][j];
            if (bias) v += bias[n];
            C[(long)m * ldc + n] = v;
        }
    }
}

// ---------------------------------------------------------------------------
// Weight pre-transpose kernels.
//  enc (unchanged layout): WtE f4 idx ((dir*16+jg)*128 + l4)*128 + jj,
//       jj: gate=jj&3, kl=jj>>2, jglob = gate*512 + jg*32 + kl.
//  dec (Whh only): Wt2 f4 idx ((jg2*128 + l4)*16 + r), r = kl*4+g,
//       jglob = g*512 + jg2*4 + kl, value = Whh[jglob][l4*4..+3].
// ---------------------------------------------------------------------------
__global__ __launch_bounds__(256)
void enc_wt_kernel(const float* __restrict__ Wf, const float* __restrict__ Wb,
                   float4* __restrict__ Wt)
{
    const int F = blockIdx.x * 256 + threadIdx.x;
    if (F >= 2 * 16 * 128 * 128) return;
    const int jj = F & 127;
    const int l4 = (F >> 7) & 127;
    const int r  = F >> 14;                 // dir*16 + jg
    const int dir = r >> 4, jg = r & 15;
    const int jglob = (jj & 3) * 512 + jg * 32 + (jj >> 2);
    const float* src = dir ? Wb : Wf;
    Wt[F] = *reinterpret_cast<const float4*>(src + (size_t)jglob * 512 + l4 * 4);
}

__global__ __launch_bounds__(256)
void dec_wt_kernel(const float* __restrict__ Whh, float4* __restrict__ Wt)
{
    const int F = blockIdx.x * 256 + threadIdx.x;
    if (F >= 128 * 128 * 16) return;
    const int r  = F & 15;
    const int l4 = (F >> 4) & 127;
    const int jg2 = F >> 11;
    const int jglob = (r & 3) * 512 + jg2 * 4 + (r >> 2);
    Wt[F] = *reinterpret_cast<const float4*>(Whh + (size_t)jglob * 512 + l4 * 4);
}

// permuted row-index for the G GEMM: m = jg2*16 + r -> jglob
__global__ __launch_bounds__(256)
void aidx_kernel(int* __restrict__ aidx)
{
    const int m = blockIdx.x * 256 + threadIdx.x;
    if (m >= 2048) return;
    const int r = m & 15;
    aidx[m] = (r & 3) * 512 + (m >> 4) * 4 + (r >> 2);
}

// ---------------------------------------------------------------------------
// Persistent encoder (R5 structure): 256 blocks = 2 dir x (16 jg x 8 ng).
// Changes vs R5: c-state in registers; encoder states stored to catSt
// [s][n][1024] concat layout (feeds G-GEMM + ee); ee epilogue reads catSt.
// ---------------------------------------------------------------------------
struct EncArgs {
    const float* Xf; const float* Xb;        // [50][64][2048] (incl. bias)
    const float4* WtE;
    float* hT;    // [2 dir][2 buf][32768]
    float* cT;    // [2 dir][32768]  (written only at final step)
    float* catSt; // [50][64][1024]  fwd cols 0..511, bwd cols 512..1023
    const float* energy_W; const float* energy_b;
    float* eeT;   // [50][64]
    const float* fc_hid_W; const float* fc_hid_b;
    const float* fc_cell_W; const float* fc_cell_b;
    float* dhT;   // [2 buf][32768]
    float* dcT;   // [32768]
    int* bars;    // [0]=fwd, [1]=bwd, [2]=full
};

__global__ __launch_bounds__(1024)
void enc_persistent(EncArgs a)
{
    __shared__ float actL[8 * 516];          // [n^][512 l] padded
    __shared__ float red[8 * 8 * 128];       // [lc][n^][jj]  32 KB
    const int blk = blockIdx.x;
    const int tid = threadIdx.x;
    const int lane = tid & 63;
    const int w    = tid >> 6;
    const int lc   = w >> 1;
    const int jh   = w & 1;
    const int dir  = blk >> 7;
    const int db   = blk & 127;
    const int jg   = (db & 7) * 2 + (db >> 6);   // XCD-local weight tiles
    const int ng   = (db >> 3) & 7;
    int genD = 0, genF = 0;

    const float* X   = dir ? a.Xb : a.Xf;
    float* hTd  = a.hT + (size_t)dir * 2 * 4 * HS4;
    float* cTd  = a.cT + (size_t)dir * 4 * HS4;
    const float4* Wt = a.WtE + (size_t)(dir * 16 + jg) * 128 * 128;

    // pointwise role (tid < 256): n^ = tid>>5, kl = tid&31
    const int pw_n  = ng * 8 + (tid >> 5);
    const int pw_kl = tid & 31;
    const int pw_k  = jg * 32 + pw_kl;
    const int pw_ci = (pw_k >> 2) * 256 + pw_n * 4 + (pw_k & 3);
    float c_reg = 0.f;                       // c-state lives in a register

    for (int t = 0; t < SSRC; ++t) {
        const int xoff = dir ? (SSRC - 1 - t) : t;
        const float* hbase = hTd + (size_t)(t & 1) * 4 * HS4;
        float xg0 = 0.f, xg1 = 0.f, xg2 = 0.f, xg3 = 0.f;
        if (tid < 256) {                     // X preload (cached, read-only)
            const float* Xr = X + (size_t)xoff * (NBATCH * G4H) + pw_n * G4H + pw_k;
            xg0 = Xr[0]; xg1 = Xr[512]; xg2 = Xr[1024]; xg3 = Xr[1536];
        }
        // stage h slice [8n][512] -> LDS (sc1, coalesced)
        {
            const int nh = tid & 7, l4g = tid >> 3;     // l4g 0..127
            const float* hp = hbase + ((size_t)l4g * 64 + ng * 8 + nh) * 4;
            const float2 lo = ld2_agent(hp), hi = ld2_agent(hp + 2);
            float4 v; v.x = lo.x; v.y = lo.y; v.z = hi.x; v.w = hi.y;
            *reinterpret_cast<float4*>(&actL[nh * 516 + l4g * 4]) = v;
        }
        __syncthreads();
        // GEMM: wave (lc, jh): l4 in [lc*16, lc*16+16), rows jj = jh*64+lane
        float acc[8];
#pragma unroll
        for (int q = 0; q < 8; ++q) acc[q] = 0.f;
        {
            const float4* wp = Wt + (size_t)(lc * 16) * 128 + jh * 64 + lane;
            for (int i = 0; i < 16; ++i) {
                const float4 wv = wp[(size_t)i * 128];
                const int l4 = lc * 16 + i;
#pragma unroll
                for (int q = 0; q < 8; ++q) {
                    const float4 av = *reinterpret_cast<const float4*>(&actL[q * 516 + l4 * 4]);
                    acc[q] = fmaf(av.w, wv.w, fmaf(av.z, wv.z,
                              fmaf(av.y, wv.y, fmaf(av.x, wv.x, acc[q]))));
                }
            }
        }
#pragma unroll
        for (int q = 0; q < 8; ++q) red[lc * 1024 + q * 128 + jh * 64 + lane] = acc[q];
        __syncthreads();
        if (tid < 256) {
            const int nh = tid >> 5;
            float g0 = xg0, g1 = xg1, g2 = xg2, g3 = xg3;
#pragma unroll
            for (int l2 = 0; l2 < 8; ++l2) {
                const float* rp = &red[l2 * 1024 + nh * 128 + pw_kl * 4];
                g0 += rp[0]; g1 += rp[1]; g2 += rp[2]; g3 += rp[3];
            }
            const float si = 1.f / (1.f + __expf(-g0));
            const float sf = 1.f / (1.f + __expf(-g1));
            const float so = 1.f / (1.f + __expf(-g3));
            const float tg = tanhf(g2);
            c_reg = sf * c_reg + si * tg;
            const float hn = so * tanhf(c_reg);
            st1_agent(&(hTd + (size_t)((t + 1) & 1) * 4 * HS4)[pw_ci], hn);
            st1_agent(&a.catSt[((size_t)xoff * 64 + pw_n) * 1024 + dir * 512 + pw_k], hn);
            if (t == SSRC - 1) st1_agent(&cTd[pw_ci], c_reg);
        }
        gbar(a.bars + dir, 128, genD);
    }
    gbar(a.bars + 2, 256, genF);

    // ---- phase 2: ee + decoder init states (final h/c in buffer 0) ----
    const int n = lane;
    if (blk < SSRC) {
        // ee[s][n] = catSt[s][n][:] . energy_W[512:1536] + energy_b
        const int s = blk;
        const int nl = tid & 63, ch = tid >> 6;   // ch 0..15
        const float* row = a.catSt + ((size_t)s * 64 + nl) * 1024;
        const float* We = a.energy_W + 512;
        float p = 0.f;
        for (int l4 = ch * 16; l4 < ch * 16 + 16; ++l4) {
            const float4 sv = *reinterpret_cast<const float4*>(row + l4 * 4);
            const float4 wv = *reinterpret_cast<const float4*>(We + l4 * 4);
            p += sv.x * wv.x + sv.y * wv.y + sv.z * wv.z + sv.w * wv.w;
        }
        red[ch * 64 + nl] = p;
        __syncthreads();
        if (ch == 0) {
            float sum = a.energy_b[0];
#pragma unroll
            for (int q = 0; q < 16; ++q) sum += red[q * 64 + nl];
            a.eeT[s * 64 + nl] = sum;
        }
    } else if (blk >= 64 && blk < 192) {
        const bool cell = blk >= 128;
        const int kb2 = (blk & 63) * 8;
        const float* W   = cell ? a.fc_cell_W : a.fc_hid_W;
        const float* bs  = cell ? a.fc_cell_b : a.fc_hid_b;
        const float* Afl = cell ? a.cT : a.hT;                       // dir0 buf0
        const float* Abl = cell ? (a.cT + (size_t)4 * HS4) : (a.hT + (size_t)8 * HS4);
        const int kl2 = w >> 1, lh = w & 1;
        const int k = kb2 + kl2;
        const float* Wr = W + (size_t)k * 1024;
        float acc = 0.f;
        for (int l4 = lh * 64; l4 < lh * 64 + 64; ++l4) {
            const float* pA = Afl + ((size_t)l4 * 64 + n) * 4;
            const float2 u01 = ld2_agent(pA), u23 = ld2_agent(pA + 2);
            const float4 wv = *reinterpret_cast<const float4*>(Wr + l4 * 4);
            acc += u01.x * wv.x + u01.y * wv.y + u23.x * wv.z + u23.y * wv.w;
            const float* pB = Abl + ((size_t)l4 * 64 + n) * 4;
            const float2 v01 = ld2_agent(pB), v23 = ld2_agent(pB + 2);
            const float4 wv2 = *reinterpret_cast<const float4*>(Wr + 512 + l4 * 4);
            acc += v01.x * wv2.x + v01.y * wv2.y + v23.x * wv2.z + v23.y * wv2.w;
        }
        red[(kl2 * 2 + lh) * 64 + n] = acc;
        __syncthreads();
        if (w < 8) {
            const float v = bs[kb2 + w] + red[(w * 2) * 64 + n] + red[(w * 2 + 1) * 64 + n];
            const int k2 = kb2 + w;
            const int ci = (k2 >> 2) * 256 + n * 4 + (k2 & 3);
            (cell ? a.dcT : a.dhT)[ci] = v;      // normal store; kernel-end flush
        }
    }
}

// ---------------------------------------------------------------------------
// Persistent decoder v6: 256 blocks = 128 jg2 x 2 ng. Block owns 16 gate-rows
// (4 k x 4 g, k = jg2*4+kl) x 32 batch. Whh tile (32 KB) staged to LDS ONCE.
// Per step (ONE grid barrier):
//   A: Whh@h partials (h via sc1) + hdot partials piggybacked on same loads
//   B: local softmax (block's 32 n)  C: G-weighted sum (G from L2, immutable)
//   D: combine + LSTM pointwise (c in registers) -> h' (sc1)
// gates_ctx identity: W_ctx @ (sum_s attn_s state_s) = sum_s attn_s G[:,s,:].
// ---------------------------------------------------------------------------
struct DecArgs {
    const float* Xd;        // [49][64][2048] (emb part + bias)
    const float4* Wt2;      // [128][128][16] f4 transposed dec_Whh
    const float* G;         // [2048 perm rows][3200]  (= Wih_ctx @ states)
    const float* Wh;        // energy_W[0..511]
    const float* eeT;       // [50][64]
    float* dhT;             // [2 buf][32768]
    const float* dcT;       // init c
    float* HsT;             // [512][3136]
    int* bar;
};

__global__ __launch_bounds__(1024)
void dec_persistent(DecArgs a)
{
    __shared__ float4 WdL[128 * 16];   // 32 KB  [l4][r]
    __shared__ float  WhL[512];
    __shared__ float  eeL[SSRC * 32];
    __shared__ float  red[16 * 512];   // [w][nl*16+r] h-part partials, 32 KB
    __shared__ float  red2[16 * 32];   // hdot partials [w][nl]
    __shared__ float  red3[16 * 32 * 2]; // G partials [r][nl][sh]
    __shared__ float  attnL[SSRC * 32];
    const int blk = blockIdx.x;
    const int tid = threadIdx.x;
    const int jg2 = blk >> 1;
    const int ng  = blk & 1;
    const int lane = tid & 63, w = tid >> 6;
    const int r = lane & 15, ns = lane >> 4;
    int gen = 0;

    for (int i = tid; i < 2048; i += 1024) WdL[i] = a.Wt2[(size_t)jg2 * 2048 + i];
    if (tid < 512) WhL[tid] = a.Wh[tid];
    for (int i = tid; i < SSRC * 32; i += 1024)
        eeL[i] = a.eeT[(i >> 5) * 64 + ng * 32 + (i & 31)];
    __syncthreads();

    // pointwise identity (tid < 128): kl = tid>>5, nl = tid&31 (fixed across t)
    const int pw_kl = tid >> 5, pw_nl = tid & 31;
    const int pw_k = jg2 * 4 + pw_kl;
    const int pw_n = ng * 32 + pw_nl;
    const int pw_ci = (pw_k >> 2) * 256 + pw_n * 4 + (pw_k & 3);
    float c_reg = 0.f;
    if (tid < 128) c_reg = ld1_agent(&a.dcT[pw_ci]);

    for (int t = 0; t < TSTEPS; ++t) {
        const float* hc = a.dhT + (size_t)(t & 1) * 32768;
        float xg0 = 0.f, xg1 = 0.f, xg2 = 0.f, xg3 = 0.f;
        if (tid < 128) {                     // X preload, non-temporal (no reuse)
            const float* Xr = a.Xd + (size_t)t * (NBATCH * G4H) + pw_n * G4H + pw_k;
            xg0 = __builtin_nontemporal_load(Xr);
            xg1 = __builtin_nontemporal_load(Xr + 512);
            xg2 = __builtin_nontemporal_load(Xr + 1024);
            xg3 = __builtin_nontemporal_load(Xr + 1536);
        }
        // A: Whh@h partials + hdot partials (same h loads)
        float acc[8], hdp[8];
#pragma unroll
        for (int q = 0; q < 8; ++q) { acc[q] = 0.f; hdp[q] = 0.f; }
        for (int i = 0; i < 8; ++i) {
            const int l4 = w * 8 + i;
            const float4 wv  = WdL[l4 * 16 + r];
            const float4 whv = *reinterpret_cast<const float4*>(&WhL[l4 * 4]);
#pragma unroll
            for (int it = 0; it < 8; ++it) {
                const int n = ng * 32 + it * 4 + ns;
                const float* hp = hc + ((size_t)l4 * 64 + n) * 4;
                const float2 lo = ld2_agent(hp), hi = ld2_agent(hp + 2);
                acc[it] = fmaf(hi.y, wv.w, fmaf(hi.x, wv.z,
                           fmaf(lo.y, wv.y, fmaf(lo.x, wv.x, acc[it]))));
                if (r == 0)
                    hdp[it] = fmaf(hi.y, whv.w, fmaf(hi.x, whv.z,
                               fmaf(lo.y, whv.y, fmaf(lo.x, whv.x, hdp[it]))));
            }
        }
#pragma unroll
        for (int it = 0; it < 8; ++it) red[w * 512 + (it * 4 + ns) * 16 + r] = acc[it];
        if (r == 0) {
#pragma unroll
            for (int it = 0; it < 8; ++it) red2[w * 32 + it * 4 + ns] = hdp[it];
        }
        __syncthreads();
        // B: hdot reduce + softmax for this block's 32 n (relu>=0 => m init 0)
        if (tid < 32) {
            float hd = 0.f;
#pragma unroll
            for (int q = 0; q < 16; ++q) hd += red2[q * 32 + tid];
            float m = 0.f;
            for (int s = 0; s < SSRC; ++s) m = fmaxf(m, hd + eeL[s * 32 + tid]);
            float ssum = 0.f;
            for (int s = 0; s < SSRC; ++s) {
                float e = hd + eeL[s * 32 + tid];
                e = e > 0.f ? e : 0.f;
                const float ex = __expf(e - m);
                attnL[s * 32 + tid] = ex;
                ssum += ex;
            }
            const float inv = 1.f / ssum;
            for (int s = 0; s < SSRC; ++s) attnL[s * 32 + tid] *= inv;
        }
        __syncthreads();
        // C: G-weighted sum (G rows immutable, L2/L3 cached)
        {
            const int nl3 = tid & 31, r3 = (tid >> 5) & 15, sh = tid >> 9;
            const float* Gp = a.G + (size_t)(jg2 * 16 + r3) * 3200 + ng * 32 + nl3;
            float gacc = 0.f;
            for (int s = sh * 25; s < sh * 25 + 25; ++s)
                gacc = fmaf(attnL[s * 32 + nl3], Gp[(size_t)s * 64], gacc);
            red3[(r3 * 32 + nl3) * 2 + sh] = gacc;
        }
        __syncthreads();
        // D: combine + LSTM pointwise
        if (tid < 128) {
            float g4[4];
#pragma unroll
            for (int g = 0; g < 4; ++g) {
                const int rr = pw_kl * 4 + g;
                float v = red3[(rr * 32 + pw_nl) * 2] + red3[(rr * 32 + pw_nl) * 2 + 1];
#pragma unroll
                for (int q = 0; q < 16; ++q) v += red[q * 512 + pw_nl * 16 + rr];
                g4[g] = v;
            }
            g4[0] += xg0; g4[1] += xg1; g4[2] += xg2; g4[3] += xg3;
            const float si = 1.f / (1.f + __expf(-g4[0]));
            const float sf = 1.f / (1.f + __expf(-g4[1]));
            const float so = 1.f / (1.f + __expf(-g4[3]));
            const float tg = tanhf(g4[2]);
            c_reg = sf * c_reg + si * tg;
            const float hn = so * tanhf(c_reg);
            st1_agent(&(a.dhT + (size_t)((t + 1) & 1) * 32768)[pw_ci], hn);
            st1_agent(&a.HsT[(size_t)pw_k * (TSTEPS * NBATCH) + t * 64 + pw_n], hn);
        }
        gbar(a.bar, 256, gen);
    }
}

// ---------------------------------------------------------------------------
extern "C" void kernel_launch(void* const* d_in, const int* in_sizes, int n_in,
                              void* d_out, int out_size, void* d_ws, size_t ws_size,
                              hipStream_t stream)
{
    const int*   source    = (const int*)  d_in[0];
    const int*   target    = (const int*)  d_in[1];
    const float* enc_emb   = (const float*)d_in[2];
    const float* enc_Wih_f = (const float*)d_in[3];
    const float* enc_Whh_f = (const float*)d_in[4];
    const float* enc_b_f   = (const float*)d_in[5];
    const float* enc_Wih_b = (const float*)d_in[6];
    const float* enc_Whh_b = (const float*)d_in[7];
    const float* enc_b_b   = (const float*)d_in[8];
    const float* fc_hid_W  = (const float*)d_in[9];
    const float* fc_hid_b  = (const float*)d_in[10];
    const float* fc_cell_W = (const float*)d_in[11];
    const float* fc_cell_b = (const float*)d_in[12];
    const float* dec_emb   = (const float*)d_in[13];
    const float* dec_Wih   = (const float*)d_in[14];
    const float* dec_Whh   = (const float*)d_in[15];
    const float* dec_b     = (const float*)d_in[16];
    const float* energy_W  = (const float*)d_in[17];
    const float* energy_b  = (const float*)d_in[18];
    const float* fc_W      = (const float*)d_in[19];
    const float* fc_b      = (const float*)d_in[20];
    float* out = (float*)d_out;

    float* w = (float*)d_ws;
    size_t o = 0;
    auto alloc = [&](size_t nf) { float* p = w + o; o += nf; return p; };
    const size_t HS = (size_t)NBATCH * HDIM;            // 32768 floats
    float* Xf    = alloc((size_t)SSRC * NBATCH * G4H);  // 6.55M
    float* Xb    = alloc((size_t)SSRC * NBATCH * G4H);  // 6.55M (G aliases this)
    float* catSt = alloc((size_t)SSRC * NBATCH * 1024); // 3.28M
    float* hT    = alloc(4 * HS);
    float* cT    = alloc(2 * HS);
    float* dhT   = alloc(2 * HS);
    float* dcT   = alloc(1 * HS);
    float* eeT   = alloc((size_t)SSRC * NBATCH);
    float* HsT   = alloc((size_t)HDIM * TSTEPS * NBATCH);   // [512][3136]
    float* WtE   = alloc((size_t)2 * 16 * 128 * 512);       // 2.10M
    float* Wt2   = alloc((size_t)128 * 128 * 16 * 4);       // 1.05M
    int*   aidxA = (int*)alloc(2048);
    int*   bars  = (int*)alloc(16);
    float* Xd    = Xf;   // alias: enc X buffer reused for decoder emb GEMM
    float* G     = Xb;   // alias: Xb dead after encoder; G = 2048 x 3200

    hipMemsetAsync(hT, 0, 4 * HS * sizeof(float), stream);
    hipMemsetAsync(bars, 0, 16 * sizeof(int), stream);
    hipMemsetAsync(out, 0, (size_t)NBATCH * VTGT * sizeof(float), stream);

    // encoder input GEMMs (embedding gather fused): X = emb[source] @ Wih.T + b
    {
        dim3 g(G4H / 128, (SSRC * NBATCH + 127) / 128);
        gemm_bias_kernel<<<g, 256, 0, stream>>>(enc_emb, source, EDIM, enc_Wih_f, EDIM,
                                                enc_b_f, Xf, G4H, SSRC * NBATCH, G4H, EDIM, 0);
        gemm_bias_kernel<<<g, 256, 0, stream>>>(enc_emb, source, EDIM, enc_Wih_b, EDIM,
                                                enc_b_b, Xb, G4H, SSRC * NBATCH, G4H, EDIM, 0);
    }
    enc_wt_kernel<<<(2 * 16 * 128 * 128 + 255) / 256, 256, 0, stream>>>(
        enc_Whh_f, enc_Whh_b, (float4*)WtE);
    aidx_kernel<<<8, 256, 0, stream>>>(aidxA);

    // persistent encoder (50 steps + ee + init states + catSt)
    {
        EncArgs ea{Xf, Xb, (const float4*)WtE, hT, cT, catSt,
                   energy_W, energy_b, eeT, fc_hid_W, fc_hid_b, fc_cell_W, fc_cell_b,
                   dhT, dcT, bars};
        enc_persistent<<<256, 1024, 0, stream>>>(ea);
    }

    // decoder embedding contribution (reuses Xf buffer)
    {
        dim3 g(G4H / 128, (TSTEPS * NBATCH + 127) / 128);
        gemm_bias_kernel<<<g, 256, 0, stream>>>(dec_emb, target, EDIM, dec_Wih + 2 * HDIM,
                                                2 * HDIM + EDIM, dec_b, Xd, G4H,
                                                TSTEPS * NBATCH, G4H, EDIM, 0);
    }
    // G = dec_Wih[:, :1024] @ catSt^T  (rows permuted to block-tile order)
    {
        dim3 g(3200 / 128, 2048 / 128);
        gemm_bias_kernel<<<g, 256, 0, stream>>>(dec_Wih, aidxA, 2 * HDIM + EDIM,
                                                catSt, 1024, nullptr,
                                                G, 3200, 2048, 3200, 1024, 0);
    }
    dec_wt_kernel<<<(128 * 128 * 16 + 255) / 256, 256, 0, stream>>>(dec_Whh, (float4*)Wt2);

    // persistent decoder (49 steps, 1 barrier/step)
    {
        DecArgs da{Xd, (const float4*)Wt2, G, energy_W, eeT,
                   dhT, dcT, HsT, bars + 3};
        dec_persistent<<<256, 1024, 0, stream>>>(da);
    }

    // deferred output projection: preds = Hs @ fc_W.T + fc_b -> out[1:]
    // HsT is [K=512][M=3136] (transposed A path).
    {
        dim3 g((VTGT + 127) / 128, (TSTEPS * NBATCH + 127) / 128);
        gemm_bias_kernel<<<g, 256, 0, stream>>>(HsT, nullptr, TSTEPS * NBATCH, fc_W, HDIM,
                                                fc_b, out + (size_t)NBATCH * VTGT, VTGT,
                                                TSTEPS * NBATCH, VTGT, HDIM, 1);
    }
}

// Round 7
// 3799.835 us; speedup vs baseline: 1.2614x; 1.2614x over previous
//
#include <hip/hip_runtime.h>
#include <math.h>

// Problem dims
#define SSRC 50
#define NBATCH 64
#define EDIM 300
#define HDIM 512
#define G4H 2048
#define VTGT 10000
#define TSTEPS 49

// Transposed-interleaved state layout: value (k, n) lives at float index
//   (k>>2)*256 + n*4 + (k&3)   i.e. float4 index [k/4][n], lane-coalesced.
#define HS4 8192          // float4 count of one 64x512 state (32768 floats)

// ---------------------------------------------------------------------------
// Agent-coherent (sc1, L2-bypassing, L3-coherent) accessors for MUTABLE shared
// state AND for streamed read-only data that must not pollute L2 (states).
// ---------------------------------------------------------------------------
__device__ __forceinline__ float ld1_agent(const float* p) {
    return __hip_atomic_load(p, __ATOMIC_RELAXED, __HIP_MEMORY_SCOPE_AGENT);
}
__device__ __forceinline__ void st1_agent(float* p, float v) {
    __hip_atomic_store(p, v, __ATOMIC_RELAXED, __HIP_MEMORY_SCOPE_AGENT);
}
__device__ __forceinline__ float2 ld2_agent(const float* p) {
    unsigned long long u = __hip_atomic_load((const unsigned long long*)p,
                                             __ATOMIC_RELAXED, __HIP_MEMORY_SCOPE_AGENT);
    union { unsigned long long u; float2 f; } c; c.u = u; return c.f;
}
__device__ __forceinline__ void st2_agent(float* p, float x, float y) {
    union { float2 f; unsigned long long u; } c; c.f.x = x; c.f.y = y;
    __hip_atomic_store((unsigned long long*)p, c.u, __ATOMIC_RELAXED, __HIP_MEMORY_SCOPE_AGENT);
}

// ---------------------------------------------------------------------------
// Fence-free device barrier (R4+-verified).
// ---------------------------------------------------------------------------
__device__ __forceinline__ void gbar(int* cnt, int nblk, int& gen)
{
    asm volatile("s_waitcnt vmcnt(0)" ::: "memory");
    __syncthreads();
    if (threadIdx.x == 0) {
        __hip_atomic_fetch_add(cnt, 1, __ATOMIC_RELAXED, __HIP_MEMORY_SCOPE_AGENT);
        gen += nblk;
        const long long t0 = (long long)__builtin_amdgcn_s_memrealtime();
        while (__hip_atomic_load(cnt, __ATOMIC_RELAXED, __HIP_MEMORY_SCOPE_AGENT) < gen) {
            __builtin_amdgcn_s_sleep(2);
            if ((long long)__builtin_amdgcn_s_memrealtime() - t0 > 200000000LL) break;
        }
    }
    __syncthreads();
}

// ---------------------------------------------------------------------------
// Generic tiled fp32 GEMM (R4-verified, LDS XOR-swizzle).
// ---------------------------------------------------------------------------
__device__ __forceinline__ int gswz(int kk, int c) {
    return kk * 128 + ((c ^ (((c >> 6) & 1) << 2)) ^ (kk << 2));
}

__global__ __launch_bounds__(256)
void gemm_bias_kernel(const float* __restrict__ A, const int* __restrict__ aidx, int lda,
                      const float* __restrict__ B, int ldb,
                      const float* __restrict__ bias,
                      float* __restrict__ C, int ldc,
                      int M, int N, int K, int a_trans)
{
    __shared__ float As[8 * 128];
    __shared__ float Bs[8 * 128];
    const int tid = threadIdx.x;
    const int bm = blockIdx.y * 128;
    const int bn = blockIdx.x * 128;
    const int tx = tid & 15;
    const int ty = tid >> 4;

    float acc[8][8];
#pragma unroll
    for (int i = 0; i < 8; ++i)
#pragma unroll
        for (int j = 0; j < 8; ++j) acc[i][j] = 0.f;

    for (int k0 = 0; k0 < K; k0 += 8) {
#pragma unroll
        for (int i = 0; i < 4; ++i) {
            int idx = tid + i * 256;
            {
                int r, kk;
                if (a_trans) { r = idx & 127; kk = idx >> 7; }
                else         { r = idx >> 3; kk = idx & 7; }
                int gm = bm + r, gk = k0 + kk;
                float va = 0.f;
                if (gm < M && gk < K) {
                    if (a_trans) va = A[(long)gk * lda + gm];
                    else {
                        long arow = aidx ? (long)aidx[gm] : (long)gm;
                        va = A[arow * (long)lda + gk];
                    }
                }
                As[gswz(kk, r)] = va;
            }
            {
                int r = idx >> 3, kk = idx & 7;
                int gn = bn + r, gk = k0 + kk;
                float vb = 0.f;
                if (gn < N && gk < K) vb = B[(long)gn * ldb + gk];
                Bs[gswz(kk, r)] = vb;
            }
        }
        __syncthreads();
#pragma unroll
        for (int kk = 0; kk < 8; ++kk) {
            const float4 a0 = *reinterpret_cast<const float4*>(&As[gswz(kk, ty * 8)]);
            const float4 a1 = *reinterpret_cast<const float4*>(&As[gswz(kk, ty * 8 + 4)]);
            const float4 b0 = *reinterpret_cast<const float4*>(&Bs[gswz(kk, tx * 8)]);
            const float4 b1 = *reinterpret_cast<const float4*>(&Bs[gswz(kk, tx * 8 + 4)]);
            const float a[8] = {a0.x, a0.y, a0.z, a0.w, a1.x, a1.y, a1.z, a1.w};
            const float b[8] = {b0.x, b0.y, b0.z, b0.w, b1.x, b1.y, b1.z, b1.w};
#pragma unroll
            for (int i = 0; i < 8; ++i)
#pragma unroll
                for (int j = 0; j < 8; ++j)
                    acc[i][j] = fmaf(a[i], b[j], acc[i][j]);
        }
        __syncthreads();
    }

#pragma unroll
    for (int i = 0; i < 8; ++i) {
        int m = bm + ty * 8 + i;
        if (m >= M) continue;
#pragma unroll
        for (int j = 0; j < 8; ++j) {
            int n = bn + tx * 8 + j;
            if (n >= N) continue;
            float v = acc[i][j];
            if (bias) v += bias[n];
            C[(long)m * ldc + n] = v;
        }
    }
}

// ---------------------------------------------------------------------------
// Weight pre-transpose kernels.
//  enc: WtE f4 idx ((dir*16+jg)*128 + l4)*128 + jj, jj: gate=jj&3, kl=jj>>2,
//       jglob = gate*512 + jg*32 + kl.
//  dec: WtD f4 idx (jg*384 + l4)*64 + j, j: gate=j&3, kl=j>>2,
//       jglob = gate*512 + jg*16 + kl; l<1024 from Wih (ctx cols), else Whh.
// ---------------------------------------------------------------------------
__global__ __launch_bounds__(256)
void enc_wt_kernel(const float* __restrict__ Wf, const float* __restrict__ Wb,
                   float4* __restrict__ Wt)
{
    const int F = blockIdx.x * 256 + threadIdx.x;
    if (F >= 2 * 16 * 128 * 128) return;
    const int jj = F & 127;
    const int l4 = (F >> 7) & 127;
    const int r  = F >> 14;                 // dir*16 + jg
    const int dir = r >> 4, jg = r & 15;
    const int jglob = (jj & 3) * 512 + jg * 32 + (jj >> 2);
    const float* src = dir ? Wb : Wf;
    Wt[F] = *reinterpret_cast<const float4*>(src + (size_t)jglob * 512 + l4 * 4);
}

__global__ __launch_bounds__(256)
void dec_wt_kernel(const float* __restrict__ Wih, const float* __restrict__ Whh,
                   float4* __restrict__ Wt)
{
    const int F = blockIdx.x * 256 + threadIdx.x;
    if (F >= 32 * 384 * 64) return;
    const int j = F & 63;
    const int t = F >> 6;                   // jg*384 + l4
    const int l4 = t % 384, jg = t / 384;
    const int jglob = (j & 3) * 512 + jg * 16 + (j >> 2);
    const int l = l4 * 4;
    float4 v;
    if (l < 1024) v = *reinterpret_cast<const float4*>(Wih + (size_t)jglob * 1324 + l);
    else          v = *reinterpret_cast<const float4*>(Whh + (size_t)jglob * 512 + (l - 1024));
    Wt[F] = v;
}

// ---------------------------------------------------------------------------
// Persistent encoder (unchanged from R6; verified).
// ---------------------------------------------------------------------------
struct EncArgs {
    const float* Xf; const float* Xb;        // [50][64][2048] (incl. bias)
    const float4* WtE;
    float* hT;    // [2 dir][2 buf][32768]
    float* cT;    // [2 dir][32768]  (written only at final step)
    float* catSt; // [50][64][1024]  fwd cols 0..511, bwd cols 512..1023
    const float* energy_W; const float* energy_b;
    float* eeT;   // [50][64]
    const float* fc_hid_W; const float* fc_hid_b;
    const float* fc_cell_W; const float* fc_cell_b;
    float* dhT;   // [2 buf][32768]
    float* dcT;   // [32768]
    int* bars;    // [0]=fwd, [1]=bwd, [2]=full
};

__global__ __launch_bounds__(1024)
void enc_persistent(EncArgs a)
{
    __shared__ float actL[8 * 516];          // [n^][512 l] padded
    __shared__ float red[8 * 8 * 128];       // [lc][n^][jj]  32 KB
    const int blk = blockIdx.x;
    const int tid = threadIdx.x;
    const int lane = tid & 63;
    const int w    = tid >> 6;
    const int lc   = w >> 1;
    const int jh   = w & 1;
    const int dir  = blk >> 7;
    const int db   = blk & 127;
    const int jg   = (db & 7) * 2 + (db >> 6);   // XCD-local weight tiles
    const int ng   = (db >> 3) & 7;
    int genD = 0, genF = 0;

    const float* X   = dir ? a.Xb : a.Xf;
    float* hTd  = a.hT + (size_t)dir * 2 * 4 * HS4;
    float* cTd  = a.cT + (size_t)dir * 4 * HS4;
    const float4* Wt = a.WtE + (size_t)(dir * 16 + jg) * 128 * 128;

    const int pw_n  = ng * 8 + (tid >> 5);
    const int pw_kl = tid & 31;
    const int pw_k  = jg * 32 + pw_kl;
    const int pw_ci = (pw_k >> 2) * 256 + pw_n * 4 + (pw_k & 3);
    float c_reg = 0.f;

    for (int t = 0; t < SSRC; ++t) {
        const int xoff = dir ? (SSRC - 1 - t) : t;
        const float* hbase = hTd + (size_t)(t & 1) * 4 * HS4;
        float xg0 = 0.f, xg1 = 0.f, xg2 = 0.f, xg3 = 0.f;
        if (tid < 256) {
            const float* Xr = X + (size_t)xoff * (NBATCH * G4H) + pw_n * G4H + pw_k;
            xg0 = __builtin_nontemporal_load(Xr);
            xg1 = __builtin_nontemporal_load(Xr + 512);
            xg2 = __builtin_nontemporal_load(Xr + 1024);
            xg3 = __builtin_nontemporal_load(Xr + 1536);
        }
        {
            const int nh = tid & 7, l4g = tid >> 3;     // l4g 0..127
            const float* hp = hbase + ((size_t)l4g * 64 + ng * 8 + nh) * 4;
            const float2 lo = ld2_agent(hp), hi = ld2_agent(hp + 2);
            float4 v; v.x = lo.x; v.y = lo.y; v.z = hi.x; v.w = hi.y;
            *reinterpret_cast<float4*>(&actL[nh * 516 + l4g * 4]) = v;
        }
        __syncthreads();
        float acc[8];
#pragma unroll
        for (int q = 0; q < 8; ++q) acc[q] = 0.f;
        {
            const float4* wp = Wt + (size_t)(lc * 16) * 128 + jh * 64 + lane;
            for (int i = 0; i < 16; ++i) {
                const float4 wv = wp[(size_t)i * 128];
                const int l4 = lc * 16 + i;
#pragma unroll
                for (int q = 0; q < 8; ++q) {
                    const float4 av = *reinterpret_cast<const float4*>(&actL[q * 516 + l4 * 4]);
                    acc[q] = fmaf(av.w, wv.w, fmaf(av.z, wv.z,
                              fmaf(av.y, wv.y, fmaf(av.x, wv.x, acc[q]))));
                }
            }
        }
#pragma unroll
        for (int q = 0; q < 8; ++q) red[lc * 1024 + q * 128 + jh * 64 + lane] = acc[q];
        __syncthreads();
        if (tid < 256) {
            const int nh = tid >> 5;
            float g0 = xg0, g1 = xg1, g2 = xg2, g3 = xg3;
#pragma unroll
            for (int l2 = 0; l2 < 8; ++l2) {
                const float* rp = &red[l2 * 1024 + nh * 128 + pw_kl * 4];
                g0 += rp[0]; g1 += rp[1]; g2 += rp[2]; g3 += rp[3];
            }
            const float si = 1.f / (1.f + __expf(-g0));
            const float sf = 1.f / (1.f + __expf(-g1));
            const float so = 1.f / (1.f + __expf(-g3));
            const float tg = tanhf(g2);
            c_reg = sf * c_reg + si * tg;
            const float hn = so * tanhf(c_reg);
            st1_agent(&(hTd + (size_t)((t + 1) & 1) * 4 * HS4)[pw_ci], hn);
            st1_agent(&a.catSt[((size_t)xoff * 64 + pw_n) * 1024 + dir * 512 + pw_k], hn);
            if (t == SSRC - 1) st1_agent(&cTd[pw_ci], c_reg);
        }
        gbar(a.bars + dir, 128, genD);
    }
    gbar(a.bars + 2, 256, genF);

    // ---- phase 2: ee + decoder init states ----
    const int n = lane;
    if (blk < SSRC) {
        const int s = blk;
        const int nl = tid & 63, ch = tid >> 6;
        const float* row = a.catSt + ((size_t)s * 64 + nl) * 1024;
        const float* We = a.energy_W + 512;
        float p = 0.f;
        for (int l4 = ch * 16; l4 < ch * 16 + 16; ++l4) {
            const float2 s01 = ld2_agent(row + l4 * 4);
            const float2 s23 = ld2_agent(row + l4 * 4 + 2);
            const float4 wv = *reinterpret_cast<const float4*>(We + l4 * 4);
            p += s01.x * wv.x + s01.y * wv.y + s23.x * wv.z + s23.y * wv.w;
        }
        red[ch * 64 + nl] = p;
        __syncthreads();
        if (ch == 0) {
            float sum = a.energy_b[0];
#pragma unroll
            for (int q = 0; q < 16; ++q) sum += red[q * 64 + nl];
            a.eeT[s * 64 + nl] = sum;
        }
    } else if (blk >= 64 && blk < 192) {
        const bool cell = blk >= 128;
        const int kb2 = (blk & 63) * 8;
        const float* W   = cell ? a.fc_cell_W : a.fc_hid_W;
        const float* bs  = cell ? a.fc_cell_b : a.fc_hid_b;
        const float* Afl = cell ? a.cT : a.hT;                       // dir0 buf0
        const float* Abl = cell ? (a.cT + (size_t)4 * HS4) : (a.hT + (size_t)8 * HS4);
        const int kl2 = w >> 1, lh = w & 1;
        const int k = kb2 + kl2;
        const float* Wr = W + (size_t)k * 1024;
        float acc = 0.f;
        for (int l4 = lh * 64; l4 < lh * 64 + 64; ++l4) {
            const float* pA = Afl + ((size_t)l4 * 64 + n) * 4;
            const float2 u01 = ld2_agent(pA), u23 = ld2_agent(pA + 2);
            const float4 wv = *reinterpret_cast<const float4*>(Wr + l4 * 4);
            acc += u01.x * wv.x + u01.y * wv.y + u23.x * wv.z + u23.y * wv.w;
            const float* pB = Abl + ((size_t)l4 * 64 + n) * 4;
            const float2 v01 = ld2_agent(pB), v23 = ld2_agent(pB + 2);
            const float4 wv2 = *reinterpret_cast<const float4*>(Wr + 512 + l4 * 4);
            acc += v01.x * wv2.x + v01.y * wv2.y + v23.x * wv2.z + v23.y * wv2.w;
        }
        red[(kl2 * 2 + lh) * 64 + n] = acc;
        __syncthreads();
        if (w < 8) {
            const float v = bs[kb2 + w] + red[(w * 2) * 64 + n] + red[(w * 2 + 1) * 64 + n];
            const int k2 = kb2 + w;
            const int ci = (k2 >> 2) * 256 + n * 4 + (k2 & 3);
            (cell ? a.dcT : a.dhT)[ci] = v;      // normal store; kernel-end flush
        }
    }
}

// ---------------------------------------------------------------------------
// Persistent decoder v7: 256 blocks = 32 jg (64 gate-rows: 16k x 4g) x 8 ng
// (8 n). Per step, 2 barriers:
//  P1: stage h[8n][512] (sc1) -> hdot (local, redundant across jg) -> softmax
//      -> ctx l-slice [8n][32] from catSt via sc1 (no L2 pollution) -> ctxG.
//  bar. P2: stage ctx[8n][1024] (sc1) -> gate GEMM K=1536 (weights streamed
//      from L2; tile 384 KB, 4/XCD = 1.5 MB resident) -> pointwise. bar.
// ---------------------------------------------------------------------------
struct DecArgs {
    const float* Xd;        // [49][64][2048] (emb part + bias)
    const float4* WtD;      // [32][384][64] f4
    const float* Wh;        // energy_W[0..511]
    const float* eeT;       // [50][64]
    const float* catSt;     // [50][64][1024]
    float* dhT;             // [2 buf][32768]
    const float* dcT;       // init c
    float* ctxG;            // [64][1024]
    float* HsT;             // [512][3136]
    int* bar;
};

__global__ __launch_bounds__(1024)
void dec_persistent(DecArgs a)
{
    __shared__ float  actL[8][1544];    // cols 0..1023 ctx, 1024..1535 h; 49.4 KB
    __shared__ float  red[16 * 544];    // [w][nh*68 + j]  34.8 KB (68: bank-spread)
    __shared__ float4 cpart[16][64];    // ctx s-partials [sh][nh*8+c]  16 KB
    __shared__ float  WhL[512];
    __shared__ float  eeL[SSRC * 8];    // [s][nh]
    __shared__ float  attnL[SSRC * 8];
    __shared__ float  hdl[8];
    const int blk = blockIdx.x;
    const int tid = threadIdx.x;
    const int lane = tid & 63;
    const int w    = tid >> 6;
    const int jg   = (blk & 7) * 4 + (blk >> 6);    // 4 weight tiles per XCD
    const int ng   = (blk >> 3) & 7;
    int gen = 0;
    const float4* Wt = a.WtD + (size_t)jg * 384 * 64;

    if (tid < 512) WhL[tid] = a.Wh[tid];
    if (tid < SSRC * 8) eeL[tid] = a.eeT[(tid >> 3) * 64 + ng * 8 + (tid & 7)];
    __syncthreads();

    // pointwise identity (tid < 128): kl = tid>>3 (16), nh = tid&7
    const int pw_kl = tid >> 3, pw_nh = tid & 7;
    const int pw_k = jg * 16 + pw_kl;
    const int pw_n = ng * 8 + pw_nh;
    const int pw_ci = (pw_k >> 2) * 256 + pw_n * 4 + (pw_k & 3);
    float c_reg = 0.f;
    if (tid < 128) c_reg = ld1_agent(&a.dcT[pw_ci]);

    for (int t = 0; t < TSTEPS; ++t) {
        const float* hc = a.dhT + (size_t)(t & 1) * 32768;
        float xg0 = 0.f, xg1 = 0.f, xg2 = 0.f, xg3 = 0.f;
        if (tid < 128) {                 // X preload, non-temporal (no L2 install)
            const float* Xr = a.Xd + (size_t)t * (NBATCH * G4H) + pw_n * G4H + pw_k;
            xg0 = __builtin_nontemporal_load(Xr);
            xg1 = __builtin_nontemporal_load(Xr + 512);
            xg2 = __builtin_nontemporal_load(Xr + 1024);
            xg3 = __builtin_nontemporal_load(Xr + 1536);
        }
        // P1a: stage h[8n][512] -> actL cols 1024..1535 (sc1)
        {
            const int nh = tid & 7, l4g = tid >> 3;   // 0..127
            const float* hp = hc + ((size_t)l4g * 64 + ng * 8 + nh) * 4;
            const float2 lo = ld2_agent(hp), hi = ld2_agent(hp + 2);
            float4 v; v.x = lo.x; v.y = lo.y; v.z = hi.x; v.w = hi.y;
            *reinterpret_cast<float4*>(&actL[nh][1024 + l4g * 4]) = v;
        }
        __syncthreads();
        // P1b: hdot[nh] — wave nh (tid<512), f4-stride reads (conflict-free)
        if (w < 8) {
            const float4 h0 = *reinterpret_cast<const float4*>(&actL[w][1024 + lane * 4]);
            const float4 h1 = *reinterpret_cast<const float4*>(&actL[w][1024 + (lane + 64) * 4]);
            const float4 w0 = *reinterpret_cast<const float4*>(&WhL[lane * 4]);
            const float4 w1 = *reinterpret_cast<const float4*>(&WhL[(lane + 64) * 4]);
            float p = h0.x * w0.x + h0.y * w0.y + h0.z * w0.z + h0.w * w0.w
                    + h1.x * w1.x + h1.y * w1.y + h1.z * w1.z + h1.w * w1.w;
#pragma unroll
            for (int off = 32; off > 0; off >>= 1) p += __shfl_down(p, off);
            if (lane == 0) hdl[w] = p;
        }
        __syncthreads();
        // P1c: softmax for this block's 8 n (relu>=0 => max starts at 0)
        if (tid < 8) {
            const float hd = hdl[tid];
            float m = 0.f;
            for (int s = 0; s < SSRC; ++s) m = fmaxf(m, hd + eeL[s * 8 + tid]);
            float ssum = 0.f;
            for (int s = 0; s < SSRC; ++s) {
                float e = hd + eeL[s * 8 + tid];
                e = e > 0.f ? e : 0.f;
                const float ex = __expf(e - m);
                attnL[s * 8 + tid] = ex;
                ssum += ex;
            }
            const float inv = 1.f / ssum;
            for (int s = 0; s < SSRC; ++s) attnL[s * 8 + tid] *= inv;
        }
        __syncthreads();
        // P1d: ctx l-slice [8n][cols jg*32 .. +32] — states via sc1 (no L2)
        {
            const int sh = tid >> 6, nc = tid & 63;     // sh 0..15
            const int nh = nc >> 3, c = nc & 7;
            const float* sp = a.catSt + ((size_t)ng * 8 + nh) * 1024 + jg * 32 + c * 4;
            float4 acc4{0.f, 0.f, 0.f, 0.f};
            for (int s = sh; s < SSRC; s += 16) {
                const float aw = attnL[s * 8 + nh];
                const float* q = sp + (size_t)s * 64 * 1024;
                const float2 lo = ld2_agent(q), hi = ld2_agent(q + 2);
                acc4.x = fmaf(aw, lo.x, acc4.x);
                acc4.y = fmaf(aw, lo.y, acc4.y);
                acc4.z = fmaf(aw, hi.x, acc4.z);
                acc4.w = fmaf(aw, hi.y, acc4.w);
            }
            cpart[sh][nc] = acc4;
        }
        __syncthreads();
        if (tid < 64) {
            const int nh = tid >> 3, c = tid & 7;
            float4 s4{0.f, 0.f, 0.f, 0.f};
#pragma unroll
            for (int sh = 0; sh < 16; ++sh) {
                const float4 v = cpart[sh][tid];
                s4.x += v.x; s4.y += v.y; s4.z += v.z; s4.w += v.w;
            }
            float* cp = a.ctxG + ((size_t)ng * 8 + nh) * 1024 + jg * 32 + c * 4;
            st2_agent(cp, s4.x, s4.y);
            st2_agent(cp + 2, s4.z, s4.w);
        }
        gbar(a.bar, 256, gen);   // all ctx slices published
        // P2a: stage ctx[8n][1024] -> actL cols 0..1023 (sc1)
#pragma unroll
        for (int i = 0; i < 2; ++i) {
            const int e = tid + i * 1024;
            const int l4g = e & 255, nh = e >> 8;
            const float* cp = a.ctxG + ((size_t)ng * 8 + nh) * 1024 + l4g * 4;
            const float2 lo = ld2_agent(cp), hi = ld2_agent(cp + 2);
            float4 v; v.x = lo.x; v.y = lo.y; v.z = hi.x; v.w = hi.y;
            *reinterpret_cast<float4*>(&actL[nh][l4g * 4]) = v;
        }
        __syncthreads();
        // P2b: gate GEMM K=1536, weights streamed from L2 (tile L2-resident)
        float acc[8];
#pragma unroll
        for (int q = 0; q < 8; ++q) acc[q] = 0.f;
        {
            const float4* wp = Wt + (size_t)(w * 24) * 64 + lane;
            for (int i = 0; i < 24; ++i) {
                const float4 wv = wp[(size_t)i * 64];
                const int l4 = w * 24 + i;
#pragma unroll
                for (int q = 0; q < 8; ++q) {
                    const float4 av = *reinterpret_cast<const float4*>(&actL[q][l4 * 4]);
                    acc[q] = fmaf(av.w, wv.w, fmaf(av.z, wv.z,
                              fmaf(av.y, wv.y, fmaf(av.x, wv.x, acc[q]))));
                }
            }
        }
#pragma unroll
        for (int q = 0; q < 8; ++q) red[w * 544 + q * 68 + lane] = acc[q];
        __syncthreads();
        // P2c: combine + LSTM pointwise
        if (tid < 128) {
            float g4[4];
#pragma unroll
            for (int g = 0; g < 4; ++g) {
                const int j = pw_kl * 4 + g;
                float v = 0.f;
#pragma unroll
                for (int w2 = 0; w2 < 16; ++w2) v += red[w2 * 544 + pw_nh * 68 + j];
                g4[g] = v;
            }
            g4[0] += xg0; g4[1] += xg1; g4[2] += xg2; g4[3] += xg3;
            const float si = 1.f / (1.f + __expf(-g4[0]));
            const float sf = 1.f / (1.f + __expf(-g4[1]));
            const float so = 1.f / (1.f + __expf(-g4[3]));
            const float tg = tanhf(g4[2]);
            c_reg = sf * c_reg + si * tg;
            const float hn = so * tanhf(c_reg);
            st1_agent(&(a.dhT + (size_t)((t + 1) & 1) * 32768)[pw_ci], hn);
            st1_agent(&a.HsT[(size_t)pw_k * (TSTEPS * NBATCH) + t * 64 + pw_n], hn);
        }
        gbar(a.bar, 256, gen);   // h' published; LDS/ctxG safe to reuse
    }
}

// ---------------------------------------------------------------------------
extern "C" void kernel_launch(void* const* d_in, const int* in_sizes, int n_in,
                              void* d_out, int out_size, void* d_ws, size_t ws_size,
                              hipStream_t stream)
{
    const int*   source    = (const int*)  d_in[0];
    const int*   target    = (const int*)  d_in[1];
    const float* enc_emb   = (const float*)d_in[2];
    const float* enc_Wih_f = (const float*)d_in[3];
    const float* enc_Whh_f = (const float*)d_in[4];
    const float* enc_b_f   = (const float*)d_in[5];
    const float* enc_Wih_b = (const float*)d_in[6];
    const float* enc_Whh_b = (const float*)d_in[7];
    const float* enc_b_b   = (const float*)d_in[8];
    const float* fc_hid_W  = (const float*)d_in[9];
    const float* fc_hid_b  = (const float*)d_in[10];
    const float* fc_cell_W = (const float*)d_in[11];
    const float* fc_cell_b = (const float*)d_in[12];
    const float* dec_emb   = (const float*)d_in[13];
    const float* dec_Wih   = (const float*)d_in[14];
    const float* dec_Whh   = (const float*)d_in[15];
    const float* dec_b     = (const float*)d_in[16];
    const float* energy_W  = (const float*)d_in[17];
    const float* energy_b  = (const float*)d_in[18];
    const float* fc_W      = (const float*)d_in[19];
    const float* fc_b      = (const float*)d_in[20];
    float* out = (float*)d_out;

    float* w = (float*)d_ws;
    size_t o = 0;
    auto alloc = [&](size_t nf) { float* p = w + o; o += nf; return p; };
    const size_t HS = (size_t)NBATCH * HDIM;            // 32768 floats
    float* Xf    = alloc((size_t)SSRC * NBATCH * G4H);  // 6.55M
    float* Xb    = alloc((size_t)SSRC * NBATCH * G4H);  // 6.55M (WtD aliases)
    float* catSt = alloc((size_t)SSRC * NBATCH * 1024); // 3.28M
    float* hT    = alloc(4 * HS);
    float* cT    = alloc(2 * HS);
    float* dhT   = alloc(2 * HS);
    float* dcT   = alloc(1 * HS);
    float* eeT   = alloc((size_t)SSRC * NBATCH);
    float* HsT   = alloc((size_t)HDIM * TSTEPS * NBATCH);   // [512][3136]
    float* WtE   = alloc((size_t)2 * 16 * 128 * 512);       // 2.10M
    int*   bars  = (int*)alloc(16);
    float* Xd    = Xf;   // alias: enc X buffer reused for decoder emb GEMM
    float* ctxG  = hT;   // alias: encoder hT dead once decoder starts (256 KB)
    float* WtD   = Xb;   // alias: Xb dead after encoder (3.15M <= 6.55M)

    hipMemsetAsync(hT, 0, 4 * HS * sizeof(float), stream);
    hipMemsetAsync(bars, 0, 16 * sizeof(int), stream);
    hipMemsetAsync(out, 0, (size_t)NBATCH * VTGT * sizeof(float), stream);

    // encoder input GEMMs (embedding gather fused): X = emb[source] @ Wih.T + b
    {
        dim3 g(G4H / 128, (SSRC * NBATCH + 127) / 128);
        gemm_bias_kernel<<<g, 256, 0, stream>>>(enc_emb, source, EDIM, enc_Wih_f, EDIM,
                                                enc_b_f, Xf, G4H, SSRC * NBATCH, G4H, EDIM, 0);
        gemm_bias_kernel<<<g, 256, 0, stream>>>(enc_emb, source, EDIM, enc_Wih_b, EDIM,
                                                enc_b_b, Xb, G4H, SSRC * NBATCH, G4H, EDIM, 0);
    }
    enc_wt_kernel<<<(2 * 16 * 128 * 128 + 255) / 256, 256, 0, stream>>>(
        enc_Whh_f, enc_Whh_b, (float4*)WtE);

    // persistent encoder (50 steps + ee + init states + catSt)
    {
        EncArgs ea{Xf, Xb, (const float4*)WtE, hT, cT, catSt,
                   energy_W, energy_b, eeT, fc_hid_W, fc_hid_b, fc_cell_W, fc_cell_b,
                   dhT, dcT, bars};
        enc_persistent<<<256, 1024, 0, stream>>>(ea);
    }

    // decoder embedding contribution (reuses Xf buffer)
    {
        dim3 g(G4H / 128, (TSTEPS * NBATCH + 127) / 128);
        gemm_bias_kernel<<<g, 256, 0, stream>>>(dec_emb, target, EDIM, dec_Wih + 2 * HDIM,
                                                2 * HDIM + EDIM, dec_b, Xd, G4H,
                                                TSTEPS * NBATCH, G4H, EDIM, 0);
    }
    // decoder weight transpose (into dead Xb space)
    dec_wt_kernel<<<(32 * 384 * 64 + 255) / 256, 256, 0, stream>>>(
        dec_Wih, dec_Whh, (float4*)WtD);

    // persistent decoder (49 steps, 2 barriers/step)
    {
        DecArgs da{Xd, (const float4*)WtD, energy_W, eeT, catSt,
                   dhT, dcT, ctxG, HsT, bars + 3};
        dec_persistent<<<256, 1024, 0, stream>>>(da);
    }

    // deferred output projection: preds = Hs @ fc_W.T + fc_b -> out[1:]
    {
        dim3 g((VTGT + 127) / 128, (TSTEPS * NBATCH + 127) / 128);
        gemm_bias_kernel<<<g, 256, 0, stream>>>(HsT, nullptr, TSTEPS * NBATCH, fc_W, HDIM,
                                                fc_b, out + (size_t)NBATCH * VTGT, VTGT,
                                                TSTEPS * NBATCH, VTGT, HDIM, 1);
    }
}

// Round 8
// 3452.203 us; speedup vs baseline: 1.3884x; 1.1007x over previous
//
#include <hip/hip_runtime.h>
#include <math.h>

// Problem dims
#define SSRC 50
#define NBATCH 64
#define EDIM 300
#define HDIM 512
#define G4H 2048
#define VTGT 10000
#define TSTEPS 49

// Transposed-interleaved state layout: value (k, n) lives at float index
//   (k>>2)*256 + n*4 + (k&3)   i.e. float4 index [k/4][n], lane-coalesced.
#define HS4 8192          // float4 count of one 64x512 state (32768 floats)

// ---------------------------------------------------------------------------
// Agent-coherent (sc1, L2-bypassing, L3-coherent) accessors for MUTABLE shared
// state. Read-only data uses normal cached loads; the barrier below performs
// no cache maintenance, so cached read-only data stays L2-resident.
// ---------------------------------------------------------------------------
__device__ __forceinline__ float ld1_agent(const float* p) {
    return __hip_atomic_load(p, __ATOMIC_RELAXED, __HIP_MEMORY_SCOPE_AGENT);
}
__device__ __forceinline__ void st1_agent(float* p, float v) {
    __hip_atomic_store(p, v, __ATOMIC_RELAXED, __HIP_MEMORY_SCOPE_AGENT);
}
__device__ __forceinline__ float2 ld2_agent(const float* p) {
    unsigned long long u = __hip_atomic_load((const unsigned long long*)p,
                                             __ATOMIC_RELAXED, __HIP_MEMORY_SCOPE_AGENT);
    union { unsigned long long u; float2 f; } c; c.u = u; return c.f;
}

// ---------------------------------------------------------------------------
// Fence-free device barrier (R4+-verified).
// ---------------------------------------------------------------------------
__device__ __forceinline__ void gbar(int* cnt, int nblk, int& gen)
{
    asm volatile("s_waitcnt vmcnt(0)" ::: "memory");
    __syncthreads();
    if (threadIdx.x == 0) {
        __hip_atomic_fetch_add(cnt, 1, __ATOMIC_RELAXED, __HIP_MEMORY_SCOPE_AGENT);
        gen += nblk;
        const long long t0 = (long long)__builtin_amdgcn_s_memrealtime();
        while (__hip_atomic_load(cnt, __ATOMIC_RELAXED, __HIP_MEMORY_SCOPE_AGENT) < gen) {
            __builtin_amdgcn_s_sleep(2);
            if ((long long)__builtin_amdgcn_s_memrealtime() - t0 > 200000000LL) break;
        }
    }
    __syncthreads();
}

// ---------------------------------------------------------------------------
// Generic tiled fp32 GEMM (R4-verified, LDS XOR-swizzle).
// c_mode: 0 = normal row-major C write; 1 = scatter into decoder G4 layout
//   G4[((jg*8+ng)*50 + s)*512 + jl*8 + nl], jg=m>>6, jl=m&63, s=n>>6,
//   ng=(n>>3)&7, nl=n&7.
// ---------------------------------------------------------------------------
__device__ __forceinline__ int gswz(int kk, int c) {
    return kk * 128 + ((c ^ (((c >> 6) & 1) << 2)) ^ (kk << 2));
}

__global__ __launch_bounds__(256)
void gemm_bias_kernel(const float* __restrict__ A, const int* __restrict__ aidx, int lda,
                      const float* __restrict__ B, int ldb,
                      const float* __restrict__ bias,
                      float* __restrict__ C, int ldc,
                      int M, int N, int K, int a_trans, int c_mode)
{
    __shared__ float As[8 * 128];
    __shared__ float Bs[8 * 128];
    const int tid = threadIdx.x;
    const int bm = blockIdx.y * 128;
    const int bn = blockIdx.x * 128;
    const int tx = tid & 15;
    const int ty = tid >> 4;

    float acc[8][8];
#pragma unroll
    for (int i = 0; i < 8; ++i)
#pragma unroll
        for (int j = 0; j < 8; ++j) acc[i][j] = 0.f;

    for (int k0 = 0; k0 < K; k0 += 8) {
#pragma unroll
        for (int i = 0; i < 4; ++i) {
            int idx = tid + i * 256;
            {
                int r, kk;
                if (a_trans) { r = idx & 127; kk = idx >> 7; }
                else         { r = idx >> 3; kk = idx & 7; }
                int gm = bm + r, gk = k0 + kk;
                float va = 0.f;
                if (gm < M && gk < K) {
                    if (a_trans) va = A[(long)gk * lda + gm];
                    else {
                        long arow = aidx ? (long)aidx[gm] : (long)gm;
                        va = A[arow * (long)lda + gk];
                    }
                }
                As[gswz(kk, r)] = va;
            }
            {
                int r = idx >> 3, kk = idx & 7;
                int gn = bn + r, gk = k0 + kk;
                float vb = 0.f;
                if (gn < N && gk < K) vb = B[(long)gn * ldb + gk];
                Bs[gswz(kk, r)] = vb;
            }
        }
        __syncthreads();
#pragma unroll
        for (int kk = 0; kk < 8; ++kk) {
            const float4 a0 = *reinterpret_cast<const float4*>(&As[gswz(kk, ty * 8)]);
            const float4 a1 = *reinterpret_cast<const float4*>(&As[gswz(kk, ty * 8 + 4)]);
            const float4 b0 = *reinterpret_cast<const float4*>(&Bs[gswz(kk, tx * 8)]);
            const float4 b1 = *reinterpret_cast<const float4*>(&Bs[gswz(kk, tx * 8 + 4)]);
            const float a[8] = {a0.x, a0.y, a0.z, a0.w, a1.x, a1.y, a1.z, a1.w};
            const float b[8] = {b0.x, b0.y, b0.z, b0.w, b1.x, b1.y, b1.z, b1.w};
#pragma unroll
            for (int i = 0; i < 8; ++i)
#pragma unroll
                for (int j = 0; j < 8; ++j)
                    acc[i][j] = fmaf(a[i], b[j], acc[i][j]);
        }
        __syncthreads();
    }

#pragma unroll
    for (int i = 0; i < 8; ++i) {
        int m = bm + ty * 8 + i;
        if (m >= M) continue;
#pragma unroll
        for (int j = 0; j < 8; ++j) {
            int n = bn + tx * 8 + j;
            if (n >= N) continue;
            float v = acc[i][j];
            if (bias) v += bias[n];
            if (c_mode == 0) {
                C[(long)m * ldc + n] = v;
            } else {
                const int jg = m >> 6, jl = m & 63;
                const int s = n >> 6, ng = (n >> 3) & 7, nl = n & 7;
                C[(size_t)(((jg * 8 + ng) * 50 + s) * 512) + jl * 8 + nl] = v;
            }
        }
    }
}

// ---------------------------------------------------------------------------
// Weight pre-transpose kernels.
//  enc: WtE f4 idx ((dir*16+jg)*128 + l4)*128 + jj, jj: gate=jj&3, kl=jj>>2,
//       jglob = gate*512 + jg*32 + kl.
//  dec: Wt3 f4 idx (jg*128 + l4)*64 + j, j = kl*4+g, jglob = g*512 + jg*16 + kl
//       (Whh only; ctx part handled via G).
// ---------------------------------------------------------------------------
__global__ __launch_bounds__(256)
void enc_wt_kernel(const float* __restrict__ Wf, const float* __restrict__ Wb,
                   float4* __restrict__ Wt)
{
    const int F = blockIdx.x * 256 + threadIdx.x;
    if (F >= 2 * 16 * 128 * 128) return;
    const int jj = F & 127;
    const int l4 = (F >> 7) & 127;
    const int r  = F >> 14;                 // dir*16 + jg
    const int dir = r >> 4, jg = r & 15;
    const int jglob = (jj & 3) * 512 + jg * 32 + (jj >> 2);
    const float* src = dir ? Wb : Wf;
    Wt[F] = *reinterpret_cast<const float4*>(src + (size_t)jglob * 512 + l4 * 4);
}

__global__ __launch_bounds__(256)
void dec_wt3_kernel(const float* __restrict__ Whh, float4* __restrict__ Wt)
{
    const int F = blockIdx.x * 256 + threadIdx.x;
    if (F >= 32 * 128 * 64) return;
    const int j  = F & 63;
    const int l4 = (F >> 6) & 127;
    const int jg = F >> 13;
    const int jglob = (j & 3) * 512 + jg * 16 + (j >> 2);
    Wt[F] = *reinterpret_cast<const float4*>(Whh + (size_t)jglob * 512 + l4 * 4);
}

// permuted row-index for the G GEMM: m = jg*64 + kl*4 + g -> jglob
__global__ __launch_bounds__(256)
void aidx_kernel(int* __restrict__ aidx)
{
    const int m = blockIdx.x * 256 + threadIdx.x;
    if (m >= 2048) return;
    aidx[m] = (m & 3) * 512 + (m >> 6) * 16 + ((m >> 2) & 15);
}

// ---------------------------------------------------------------------------
// Persistent encoder (unchanged from R7; verified).
// ---------------------------------------------------------------------------
struct EncArgs {
    const float* Xf; const float* Xb;        // [50][64][2048] (incl. bias)
    const float4* WtE;
    float* hT;    // [2 dir][2 buf][32768]
    float* cT;    // [2 dir][32768]  (written only at final step)
    float* catSt; // [50][64][1024]  fwd cols 0..511, bwd cols 512..1023
    const float* energy_W; const float* energy_b;
    float* eeT;   // [50][64]
    const float* fc_hid_W; const float* fc_hid_b;
    const float* fc_cell_W; const float* fc_cell_b;
    float* dhT;   // [2 buf][32768]
    float* dcT;   // [32768]
    int* bars;    // [0]=fwd, [1]=bwd, [2]=full
};

__global__ __launch_bounds__(1024)
void enc_persistent(EncArgs a)
{
    __shared__ float actL[8 * 516];          // [n^][512 l] padded
    __shared__ float red[8 * 8 * 128];       // [lc][n^][jj]  32 KB
    const int blk = blockIdx.x;
    const int tid = threadIdx.x;
    const int lane = tid & 63;
    const int w    = tid >> 6;
    const int lc   = w >> 1;
    const int jh   = w & 1;
    const int dir  = blk >> 7;
    const int db   = blk & 127;
    const int jg   = (db & 7) * 2 + (db >> 6);   // XCD-local weight tiles
    const int ng   = (db >> 3) & 7;
    int genD = 0, genF = 0;

    const float* X   = dir ? a.Xb : a.Xf;
    float* hTd  = a.hT + (size_t)dir * 2 * 4 * HS4;
    float* cTd  = a.cT + (size_t)dir * 4 * HS4;
    const float4* Wt = a.WtE + (size_t)(dir * 16 + jg) * 128 * 128;

    const int pw_n  = ng * 8 + (tid >> 5);
    const int pw_kl = tid & 31;
    const int pw_k  = jg * 32 + pw_kl;
    const int pw_ci = (pw_k >> 2) * 256 + pw_n * 4 + (pw_k & 3);
    float c_reg = 0.f;

    for (int t = 0; t < SSRC; ++t) {
        const int xoff = dir ? (SSRC - 1 - t) : t;
        const float* hbase = hTd + (size_t)(t & 1) * 4 * HS4;
        float xg0 = 0.f, xg1 = 0.f, xg2 = 0.f, xg3 = 0.f;
        if (tid < 256) {
            const float* Xr = X + (size_t)xoff * (NBATCH * G4H) + pw_n * G4H + pw_k;
            xg0 = __builtin_nontemporal_load(Xr);
            xg1 = __builtin_nontemporal_load(Xr + 512);
            xg2 = __builtin_nontemporal_load(Xr + 1024);
            xg3 = __builtin_nontemporal_load(Xr + 1536);
        }
        {
            const int nh = tid & 7, l4g = tid >> 3;     // l4g 0..127
            const float* hp = hbase + ((size_t)l4g * 64 + ng * 8 + nh) * 4;
            const float2 lo = ld2_agent(hp), hi = ld2_agent(hp + 2);
            float4 v; v.x = lo.x; v.y = lo.y; v.z = hi.x; v.w = hi.y;
            *reinterpret_cast<float4*>(&actL[nh * 516 + l4g * 4]) = v;
        }
        __syncthreads();
        float acc[8];
#pragma unroll
        for (int q = 0; q < 8; ++q) acc[q] = 0.f;
        {
            const float4* wp = Wt + (size_t)(lc * 16) * 128 + jh * 64 + lane;
            for (int i = 0; i < 16; ++i) {
                const float4 wv = wp[(size_t)i * 128];
                const int l4 = lc * 16 + i;
#pragma unroll
                for (int q = 0; q < 8; ++q) {
                    const float4 av = *reinterpret_cast<const float4*>(&actL[q * 516 + l4 * 4]);
                    acc[q] = fmaf(av.w, wv.w, fmaf(av.z, wv.z,
                              fmaf(av.y, wv.y, fmaf(av.x, wv.x, acc[q]))));
                }
            }
        }
#pragma unroll
        for (int q = 0; q < 8; ++q) red[lc * 1024 + q * 128 + jh * 64 + lane] = acc[q];
        __syncthreads();
        if (tid < 256) {
            const int nh = tid >> 5;
            float g0 = xg0, g1 = xg1, g2 = xg2, g3 = xg3;
#pragma unroll
            for (int l2 = 0; l2 < 8; ++l2) {
                const float* rp = &red[l2 * 1024 + nh * 128 + pw_kl * 4];
                g0 += rp[0]; g1 += rp[1]; g2 += rp[2]; g3 += rp[3];
            }
            const float si = 1.f / (1.f + __expf(-g0));
            const float sf = 1.f / (1.f + __expf(-g1));
            const float so = 1.f / (1.f + __expf(-g3));
            const float tg = tanhf(g2);
            c_reg = sf * c_reg + si * tg;
            const float hn = so * tanhf(c_reg);
            st1_agent(&(hTd + (size_t)((t + 1) & 1) * 4 * HS4)[pw_ci], hn);
            st1_agent(&a.catSt[((size_t)xoff * 64 + pw_n) * 1024 + dir * 512 + pw_k], hn);
            if (t == SSRC - 1) st1_agent(&cTd[pw_ci], c_reg);
        }
        gbar(a.bars + dir, 128, genD);
    }
    gbar(a.bars + 2, 256, genF);

    // ---- phase 2: ee + decoder init states ----
    const int n = lane;
    if (blk < SSRC) {
        const int s = blk;
        const int nl = tid & 63, ch = tid >> 6;
        const float* row = a.catSt + ((size_t)s * 64 + nl) * 1024;
        const float* We = a.energy_W + 512;
        float p = 0.f;
        for (int l4 = ch * 16; l4 < ch * 16 + 16; ++l4) {
            const float2 s01 = ld2_agent(row + l4 * 4);
            const float2 s23 = ld2_agent(row + l4 * 4 + 2);
            const float4 wv = *reinterpret_cast<const float4*>(We + l4 * 4);
            p += s01.x * wv.x + s01.y * wv.y + s23.x * wv.z + s23.y * wv.w;
        }
        red[ch * 64 + nl] = p;
        __syncthreads();
        if (ch == 0) {
            float sum = a.energy_b[0];
#pragma unroll
            for (int q = 0; q < 16; ++q) sum += red[q * 64 + nl];
            a.eeT[s * 64 + nl] = sum;
        }
    } else if (blk >= 64 && blk < 192) {
        const bool cell = blk >= 128;
        const int kb2 = (blk & 63) * 8;
        const float* W   = cell ? a.fc_cell_W : a.fc_hid_W;
        const float* bs  = cell ? a.fc_cell_b : a.fc_hid_b;
        const float* Afl = cell ? a.cT : a.hT;                       // dir0 buf0
        const float* Abl = cell ? (a.cT + (size_t)4 * HS4) : (a.hT + (size_t)8 * HS4);
        const int kl2 = w >> 1, lh = w & 1;
        const int k = kb2 + kl2;
        const float* Wr = W + (size_t)k * 1024;
        float acc = 0.f;
        for (int l4 = lh * 64; l4 < lh * 64 + 64; ++l4) {
            const float* pA = Afl + ((size_t)l4 * 64 + n) * 4;
            const float2 u01 = ld2_agent(pA), u23 = ld2_agent(pA + 2);
            const float4 wv = *reinterpret_cast<const float4*>(Wr + l4 * 4);
            acc += u01.x * wv.x + u01.y * wv.y + u23.x * wv.z + u23.y * wv.w;
            const float* pB = Abl + ((size_t)l4 * 64 + n) * 4;
            const float2 v01 = ld2_agent(pB), v23 = ld2_agent(pB + 2);
            const float4 wv2 = *reinterpret_cast<const float4*>(Wr + 512 + l4 * 4);
            acc += v01.x * wv2.x + v01.y * wv2.y + v23.x * wv2.z + v23.y * wv2.w;
        }
        red[(kl2 * 2 + lh) * 64 + n] = acc;
        __syncthreads();
        if (w < 8) {
            const float v = bs[kb2 + w] + red[(w * 2) * 64 + n] + red[(w * 2 + 1) * 64 + n];
            const int k2 = kb2 + w;
            const int ci = (k2 >> 2) * 256 + n * 4 + (k2 & 3);
            (cell ? a.dcT : a.dhT)[ci] = v;      // normal store; kernel-end flush
        }
    }
}

// ---------------------------------------------------------------------------
// Persistent decoder v8 (G-based, XCD-correct, ONE barrier/step).
// 256 blocks: jg = (blk&7)*4 + ((blk>>3)&3)  (4 j-tiles per XCD, L2-resident:
// G slice 3.28 MB + Whh 0.5 MB), ng = blk>>5 (8 n; all 8 ng of a jg share XCD).
// gates_ctx[j,n] = sum_s attn[s,n] * G[j,s,n]  (G = Wih_ctx @ states, precomp).
// hdot via per-block partials published with h' (no extra roundtrip).
// ---------------------------------------------------------------------------
struct DecArgs {
    const float* Xd;        // [49][64][2048] (emb part + bias)
    const float4* Wt3;      // [32][128][64] f4 (Whh per-tile transpose)
    const float* G4;        // [32 jg][8 ng][50 s][64 jl][8 n]
    const float* Wh;        // energy_W[0..511]
    const float* eeT;       // [50][64]
    float* dhT;             // [2 buf][32768]
    const float* dcT;       // init c
    float* hdP;             // [32][64] hdot partials
    float* HsT;             // [512][3136]
    int* bar;
};

__global__ __launch_bounds__(1024)
void dec_persistent(DecArgs a)
{
    __shared__ float  actL[8][520];      // h staged [nh][512]+pad  16.6 KB
    __shared__ float  red[16 * 544];     // Whh partials [w][nh*68+j] 34.8 KB
    __shared__ float4 red3[8][64][2];    // G partials [sh][jl][nhh]  16 KB
    __shared__ float  WhL[512];
    __shared__ float  eeL[SSRC][9];      // padded (bank-spread)
    __shared__ float  attnL[SSRC][8];    // f4-readable rows
    __shared__ float  hdl[8];
    __shared__ float  hdpl[32][8];
    __shared__ float  hdkl[16][8];
    const int blk = blockIdx.x;
    const int tid = threadIdx.x;
    const int lane = tid & 63, w = tid >> 6;
    const int jg = (blk & 7) * 4 + ((blk >> 3) & 3);
    const int ng = blk >> 5;
    int gen = 0;
    const float4* Wt = a.Wt3 + (size_t)jg * 128 * 64;
    const float*  Gt = a.G4 + (size_t)(jg * 8 + ng) * 50 * 512;

    if (tid < 512) WhL[tid] = a.Wh[tid];
    if (tid < SSRC * 8)
        eeL[tid >> 3][tid & 7] = a.eeT[(tid >> 3) * 64 + ng * 8 + (tid & 7)];
    __syncthreads();

    // pointwise identity (tid < 128): kl = tid>>3 (16), nh = tid&7
    const int pw_kl = tid >> 3, pw_nh = tid & 7;
    const int pw_k = jg * 16 + pw_kl;
    const int pw_n = ng * 8 + pw_nh;
    const int pw_ci = (pw_k >> 2) * 256 + pw_n * 4 + (pw_k & 3);
    float c_reg = 0.f;
    if (tid < 128) c_reg = ld1_agent(&a.dcT[pw_ci]);

    for (int t = 0; t < TSTEPS; ++t) {
        const float* hc = a.dhT + (size_t)(t & 1) * 32768;
        // stage h [8n][512] (sc1)
        {
            const int nh = tid & 7, l4g = tid >> 3;
            const float* hp = hc + ((size_t)l4g * 64 + ng * 8 + nh) * 4;
            const float2 lo = ld2_agent(hp), hi = ld2_agent(hp + 2);
            float4 v; v.x = lo.x; v.y = lo.y; v.z = hi.x; v.w = hi.y;
            *reinterpret_cast<float4*>(&actL[nh][l4g * 4]) = v;
        }
        float xg0 = 0.f, xg1 = 0.f, xg2 = 0.f, xg3 = 0.f;
        if (tid < 128) {                 // X preload, non-temporal
            const float* Xr = a.Xd + (size_t)t * (NBATCH * G4H) + pw_n * G4H + pw_k;
            xg0 = __builtin_nontemporal_load(Xr);
            xg1 = __builtin_nontemporal_load(Xr + 512);
            xg2 = __builtin_nontemporal_load(Xr + 1024);
            xg3 = __builtin_nontemporal_load(Xr + 1536);
        }
        __syncthreads();                 // actL ready
        // hd[n]: t=0 local dot; else sum published partials
        if (t == 0) {
            if (w < 8) {
                const float4 h0 = *reinterpret_cast<const float4*>(&actL[w][lane * 4]);
                const float4 h1 = *reinterpret_cast<const float4*>(&actL[w][(lane + 64) * 4]);
                const float4 w0 = *reinterpret_cast<const float4*>(&WhL[lane * 4]);
                const float4 w1 = *reinterpret_cast<const float4*>(&WhL[(lane + 64) * 4]);
                float p = h0.x * w0.x + h0.y * w0.y + h0.z * w0.z + h0.w * w0.w
                        + h1.x * w1.x + h1.y * w1.y + h1.z * w1.z + h1.w * w1.w;
#pragma unroll
                for (int off = 32; off > 0; off >>= 1) p += __shfl_down(p, off);
                if (lane == 0) hdl[w] = p;
            }
        } else {
            if (tid < 256) {
                const int q = tid >> 3, nh = tid & 7;
                hdpl[q][nh] = ld1_agent(&a.hdP[q * 64 + ng * 8 + nh]);
            }
            __syncthreads();
            if (tid < 8) {
                float s = 0.f;
#pragma unroll
                for (int q = 0; q < 32; ++q) s += hdpl[q][tid];
                hdl[tid] = s;
            }
        }
        __syncthreads();                 // hdl ready
        // softmax: wave per n (w<8), lane = s
        if (w < 8) {
            const float hd = hdl[w];
            float e = 0.f;
            if (lane < SSRC) { e = hd + eeL[lane][w]; e = e > 0.f ? e : 0.f; }
            float m = e;
#pragma unroll
            for (int off = 32; off > 0; off >>= 1) m = fmaxf(m, __shfl_xor(m, off));
            float ex = (lane < SSRC) ? __expf(e - m) : 0.f;
            float ssum = ex;
#pragma unroll
            for (int off = 32; off > 0; off >>= 1) ssum += __shfl_xor(ssum, off);
            if (lane < SSRC) attnL[lane][w] = ex / ssum;
        }
        __syncthreads();                 // attnL ready
        // G-sum (L2-resident, coalesced 32B-stride): jl=tid&63, sh, nhh
        {
            const int jl = tid & 63, sh = (tid >> 6) & 7, nhh = tid >> 9;
            const float* Gp = Gt + jl * 8 + nhh * 4;
            float4 acc4{0.f, 0.f, 0.f, 0.f};
            for (int s = sh; s < SSRC; s += 8) {
                const float4 av = *reinterpret_cast<const float4*>(&attnL[s][nhh * 4]);
                const float4 gv = *reinterpret_cast<const float4*>(Gp + (size_t)s * 512);
                acc4.x = fmaf(av.x, gv.x, acc4.x);
                acc4.y = fmaf(av.y, gv.y, acc4.y);
                acc4.z = fmaf(av.z, gv.z, acc4.z);
                acc4.w = fmaf(av.w, gv.w, acc4.w);
            }
            red3[sh][jl][nhh] = acc4;
        }
        // Whh GEMM K=512: wave w covers l4 in [w*8, w*8+8), lane = j
        {
            float acc2[8];
#pragma unroll
            for (int q = 0; q < 8; ++q) acc2[q] = 0.f;
            const float4* wp = Wt + (size_t)(w * 8) * 64 + lane;
            for (int i = 0; i < 8; ++i) {
                const float4 wv = wp[(size_t)i * 64];
                const int l4 = w * 8 + i;
#pragma unroll
                for (int q = 0; q < 8; ++q) {
                    const float4 av = *reinterpret_cast<const float4*>(&actL[q][l4 * 4]);
                    acc2[q] = fmaf(av.w, wv.w, fmaf(av.z, wv.z,
                               fmaf(av.y, wv.y, fmaf(av.x, wv.x, acc2[q]))));
                }
            }
#pragma unroll
            for (int q = 0; q < 8; ++q) red[w * 544 + q * 68 + lane] = acc2[q];
        }
        __syncthreads();                 // red, red3 ready
        // combine + LSTM pointwise + hd partials
        if (tid < 128) {
            const float* r3f = reinterpret_cast<const float*>(red3);
            const int base = pw_nh >> 2, cc = pw_nh & 3;
            float g4[4] = {xg0, xg1, xg2, xg3};
#pragma unroll
            for (int g = 0; g < 4; ++g) {
                const int j = pw_kl * 4 + g;
                float v = g4[g];
#pragma unroll
                for (int w2 = 0; w2 < 16; ++w2) v += red[w2 * 544 + pw_nh * 68 + j];
#pragma unroll
                for (int sh = 0; sh < 8; ++sh)
                    v += r3f[(size_t)(sh * 128 + j * 2 + base) * 4 + cc];
                g4[g] = v;
            }
            const float si = 1.f / (1.f + __expf(-g4[0]));
            const float sf = 1.f / (1.f + __expf(-g4[1]));
            const float so = 1.f / (1.f + __expf(-g4[3]));
            const float tg = tanhf(g4[2]);
            c_reg = sf * c_reg + si * tg;
            const float hn = so * tanhf(c_reg);
            st1_agent(&(a.dhT + (size_t)((t + 1) & 1) * 32768)[pw_ci], hn);
            st1_agent(&a.HsT[(size_t)pw_k * (TSTEPS * NBATCH) + t * 64 + pw_n], hn);
            hdkl[pw_kl][pw_nh] = WhL[pw_k] * hn;
        }
        __syncthreads();                 // hdkl ready
        if (tid < 8) {
            float s = 0.f;
#pragma unroll
            for (int kl = 0; kl < 16; ++kl) s += hdkl[kl][tid];
            st1_agent(&a.hdP[jg * 64 + ng * 8 + tid], s);
        }
        gbar(a.bar, 256, gen);           // ONE barrier per step
    }
}

// ---------------------------------------------------------------------------
extern "C" void kernel_launch(void* const* d_in, const int* in_sizes, int n_in,
                              void* d_out, int out_size, void* d_ws, size_t ws_size,
                              hipStream_t stream)
{
    const int*   source    = (const int*)  d_in[0];
    const int*   target    = (const int*)  d_in[1];
    const float* enc_emb   = (const float*)d_in[2];
    const float* enc_Wih_f = (const float*)d_in[3];
    const float* enc_Whh_f = (const float*)d_in[4];
    const float* enc_b_f   = (const float*)d_in[5];
    const float* enc_Wih_b = (const float*)d_in[6];
    const float* enc_Whh_b = (const float*)d_in[7];
    const float* enc_b_b   = (const float*)d_in[8];
    const float* fc_hid_W  = (const float*)d_in[9];
    const float* fc_hid_b  = (const float*)d_in[10];
    const float* fc_cell_W = (const float*)d_in[11];
    const float* fc_cell_b = (const float*)d_in[12];
    const float* dec_emb   = (const float*)d_in[13];
    const float* dec_Wih   = (const float*)d_in[14];
    const float* dec_Whh   = (const float*)d_in[15];
    const float* dec_b     = (const float*)d_in[16];
    const float* energy_W  = (const float*)d_in[17];
    const float* energy_b  = (const float*)d_in[18];
    const float* fc_W      = (const float*)d_in[19];
    const float* fc_b      = (const float*)d_in[20];
    float* out = (float*)d_out;

    float* w = (float*)d_ws;
    size_t o = 0;
    auto alloc = [&](size_t nf) { float* p = w + o; o += nf; return p; };
    const size_t HS = (size_t)NBATCH * HDIM;            // 32768 floats
    float* Xf    = alloc((size_t)SSRC * NBATCH * G4H);  // 6.55M
    float* Xb    = alloc((size_t)SSRC * NBATCH * G4H);  // 6.55M (G4 aliases)
    float* catSt = alloc((size_t)SSRC * NBATCH * 1024); // 3.28M
    float* hT    = alloc(4 * HS);
    float* cT    = alloc(2 * HS);
    float* dhT   = alloc(2 * HS);
    float* dcT   = alloc(1 * HS);
    float* eeT   = alloc((size_t)SSRC * NBATCH);
    float* HsT   = alloc((size_t)HDIM * TSTEPS * NBATCH);   // [512][3136]
    float* WtE   = alloc((size_t)2 * 16 * 128 * 512);       // 2.10M
    float* Wt3   = alloc((size_t)32 * 128 * 64 * 4);        // 1.05M
    float* hdP   = alloc((size_t)32 * 64);
    int*   aidxA = (int*)alloc(2048);
    int*   bars  = (int*)alloc(16);
    float* Xd    = Xf;   // alias: enc X buffer reused for decoder emb GEMM
    float* G4    = Xb;   // alias: Xb dead after encoder; G4 = 6.5536M exact

    hipMemsetAsync(hT, 0, 4 * HS * sizeof(float), stream);
    hipMemsetAsync(bars, 0, 16 * sizeof(int), stream);
    hipMemsetAsync(out, 0, (size_t)NBATCH * VTGT * sizeof(float), stream);

    // encoder input GEMMs (embedding gather fused): X = emb[source] @ Wih.T + b
    {
        dim3 g(G4H / 128, (SSRC * NBATCH + 127) / 128);
        gemm_bias_kernel<<<g, 256, 0, stream>>>(enc_emb, source, EDIM, enc_Wih_f, EDIM,
                                                enc_b_f, Xf, G4H, SSRC * NBATCH, G4H, EDIM, 0, 0);
        gemm_bias_kernel<<<g, 256, 0, stream>>>(enc_emb, source, EDIM, enc_Wih_b, EDIM,
                                                enc_b_b, Xb, G4H, SSRC * NBATCH, G4H, EDIM, 0, 0);
    }
    enc_wt_kernel<<<(2 * 16 * 128 * 128 + 255) / 256, 256, 0, stream>>>(
        enc_Whh_f, enc_Whh_b, (float4*)WtE);
    aidx_kernel<<<8, 256, 0, stream>>>(aidxA);

    // persistent encoder (50 steps + ee + init states + catSt)
    {
        EncArgs ea{Xf, Xb, (const float4*)WtE, hT, cT, catSt,
                   energy_W, energy_b, eeT, fc_hid_W, fc_hid_b, fc_cell_W, fc_cell_b,
                   dhT, dcT, bars};
        enc_persistent<<<256, 1024, 0, stream>>>(ea);
    }

    // decoder embedding contribution (reuses Xf buffer)
    {
        dim3 g(G4H / 128, (TSTEPS * NBATCH + 127) / 128);
        gemm_bias_kernel<<<g, 256, 0, stream>>>(dec_emb, target, EDIM, dec_Wih + 2 * HDIM,
                                                2 * HDIM + EDIM, dec_b, Xd, G4H,
                                                TSTEPS * NBATCH, G4H, EDIM, 0, 0);
    }
    // G = dec_Wih[:, :1024] @ catSt^T, rows permuted, scattered into G4 layout
    {
        dim3 g(3200 / 128, 2048 / 128);
        gemm_bias_kernel<<<g, 256, 0, stream>>>(dec_Wih, aidxA, 2 * HDIM + EDIM,
                                                catSt, 1024, nullptr,
                                                G4, 3200, 2048, 3200, 1024, 0, 1);
    }
    dec_wt3_kernel<<<(32 * 128 * 64 + 255) / 256, 256, 0, stream>>>(dec_Whh, (float4*)Wt3);

    // persistent decoder (49 steps, 1 barrier/step)
    {
        DecArgs da{Xd, (const float4*)Wt3, G4, energy_W, eeT,
                   dhT, dcT, hdP, HsT, bars + 3};
        dec_persistent<<<256, 1024, 0, stream>>>(da);
    }

    // deferred output projection: preds = Hs @ fc_W.T + fc_b -> out[1:]
    {
        dim3 g((VTGT + 127) / 128, (TSTEPS * NBATCH + 127) / 128);
        gemm_bias_kernel<<<g, 256, 0, stream>>>(HsT, nullptr, TSTEPS * NBATCH, fc_W, HDIM,
                                                fc_b, out + (size_t)NBATCH * VTGT, VTGT,
                                                TSTEPS * NBATCH, VTGT, HDIM, 1, 0);
    }
}